// Round 9
// baseline (833.441 us; speedup 1.0000x reference)
//
#include <hip/hip_runtime.h>
#include <hip/hip_cooperative_groups.h>
#include <hip/hip_fp16.h>
#include <math.h>

namespace cg = cooperative_groups;

#define N_NODES 100000
#define N_EDGES 1600000
#define F_IN 8
#define HID 32
#define HEADS 4
#define F1 128    // HEADS*HID
#define F2 16     // OUT
#define NB 391          // buckets of 256 nodes
#define NBLK_BIN 391    // edge-binning chunks of 4096 edges
#define BCAP 4864       // per-bucket capacity (mean 4092, sd ~64 -> 12 sigma)
#define NBLK_MAX 1280   // target cooperative grid: 5 blocks/CU x 256 CUs

__device__ __forceinline__ float leaky(float x){ return x > 0.f ? x : 0.2f * x; }
__device__ __forceinline__ float elu1(float x){ return x > 0.f ? x : __expf(x) - 1.f; }

__device__ __forceinline__ void fma8(float* acc, float w, const uint4& r){
    const __half2* p = (const __half2*)&r;
    #pragma unroll
    for (int k = 0; k < 4; k++){
        float2 f = __half22float2(p[k]);
        acc[2 * k]     += w * f.x;
        acc[2 * k + 1] += w * f.y;
    }
}

struct Params {
    const int* src; const int* dst;
    const float* x; const float* W1; const float* as1w; const float* ad1w; const float* b1;
    const float* W2; const float* as2w; const float* ad2w; const float* b2;
    const float* Wc1; const float* bc1; const float* Wc2; const float* bc2;
    float* out;
    int* bucketCnt; unsigned int* ebuf; int* row_ptr; int* esrc;
    __half* h1h; __half* hL1h; __half* h2h;
    float* a_s1; float* a_d1; float* a_s2; float* a_d2;
};

// Phases (bit i of pm): 0=zero counters, 1=bin+dense1, 2=local CSR, 3=agg1, 4=dense2, 5=agg2+clf.
// Cooperative path: pm=0x3F, grid.sync between phases. Fallback: 6 normal launches, single-bit pm.
__global__ __launch_bounds__(256, 5) void k_mega(Params p, int pm){
    cg::grid_group grid = cg::this_grid();
    const bool multi = (pm & (pm - 1)) != 0;
    __shared__ __align__(16) char smem_raw[8448];
    int t = threadIdx.x;
    int bid = blockIdx.x;
    int nb = gridDim.x;

    // ---------------- P0: zero bucket counters ----------------
    if (pm & 1){
        for (int j = bid * 256 + t; j < NB; j += nb * 256) p.bucketCnt[j] = 0;
    }
    if (multi) grid.sync();

    // ---------------- P1: edge binning (vb 0..390) + layer-1 dense (rest) ----------------
    if (pm & 2){
        for (int vb = bid; vb < NBLK_BIN + N_NODES / 8; vb += nb){
            __syncthreads();                    // smem reuse guard across virtual blocks
            if (vb < NBLK_BIN){
                int* hist    = (int*)smem_raw;
                int* basePos = hist + NB;
                int* cur     = basePos + NB;
                for (int j = t; j < NB; j += 256) hist[j] = 0;
                __syncthreads();
                int base = vb * 4096;
                #pragma unroll
                for (int j = 0; j < 16; j++){
                    int e = base + j * 256 + t;
                    if (e < N_EDGES) atomicAdd(&hist[p.dst[e] >> 8], 1);
                }
                __syncthreads();
                for (int j = t; j < NB; j += 256){
                    basePos[j] = atomicAdd(&p.bucketCnt[j], hist[j]);
                    cur[j] = 0;
                }
                __syncthreads();
                #pragma unroll
                for (int j = 0; j < 16; j++){
                    int e = base + j * 256 + t;
                    if (e < N_EDGES){
                        int d = p.dst[e];
                        int b = d >> 8;
                        int off = atomicAdd(&cur[b], 1);
                        p.ebuf[b * BCAP + basePos[b] + off] = ((unsigned)(d & 255) << 17) | (unsigned)p.src[e];
                    }
                }
            } else {
                float* W1s  = (float*)smem_raw;      // 1024
                float* atts = W1s + 1024;            // 128
                float* attd = atts + 128;            // 128
                float* xs   = attd + 128;            // 64
                int db = vb - NBLK_BIN;
                ((float4*)W1s)[t] = ((const float4*)p.W1)[t];
                if (t < 128){ atts[t] = p.as1w[t]; attd[t] = p.ad1w[t]; }
                if (t < 64) xs[t] = p.x[db * 64 + t];
                __syncthreads();

                int ln = t >> 5, l32 = t & 31;
                int n = db * 8 + ln;
                float xr[8];
                #pragma unroll
                for (int k = 0; k < 8; k++) xr[k] = xs[ln * 8 + k];
                int j0 = l32 * 4;
                float o0 = 0, o1 = 0, o2 = 0, o3 = 0;
                #pragma unroll
                for (int k = 0; k < 8; k++){
                    float4 w4 = ((const float4*)(W1s + k * F1))[l32];
                    o0 += xr[k] * w4.x; o1 += xr[k] * w4.y; o2 += xr[k] * w4.z; o3 += xr[k] * w4.w;
                }
                int hd = l32 >> 3;
                int dl = j0 & 31;
                float ps = o0 * atts[hd * 32 + dl] + o1 * atts[hd * 32 + dl + 1]
                         + o2 * atts[hd * 32 + dl + 2] + o3 * atts[hd * 32 + dl + 3];
                float pd = o0 * attd[hd * 32 + dl] + o1 * attd[hd * 32 + dl + 1]
                         + o2 * attd[hd * 32 + dl + 2] + o3 * attd[hd * 32 + dl + 3];
                ps += __shfl_down(ps, 4, 8); ps += __shfl_down(ps, 2, 8); ps += __shfl_down(ps, 1, 8);
                pd += __shfl_down(pd, 4, 8); pd += __shfl_down(pd, 2, 8); pd += __shfl_down(pd, 1, 8);
                if ((l32 & 7) == 0){ p.a_s1[n * 4 + hd] = ps; p.a_d1[n * 4 + hd] = pd; }
                __half2* hp = (__half2*)(p.h1h + (size_t)n * F1 + j0);
                hp[0] = __floats2half2_rn(o0, o1);
                hp[1] = __floats2half2_rn(o2, o3);
            }
        }
    }
    if (multi) grid.sync();

    // ---------------- P2: per-bucket CSR ----------------
    if (pm & 4){
        for (int b = bid; b < NB; b += nb){
            __syncthreads();
            int* deg    = (int*)smem_raw;
            int* scn    = deg + 256;
            int* cntAll = scn + 256;
            int* sb     = cntAll + NB;
            deg[t] = 0;
            for (int j = t; j < NB; j += 256) cntAll[j] = p.bucketCnt[j];
            __syncthreads();
            if (t == 0){
                int s = 0;
                for (int i = 0; i < b; i++) s += cntAll[i];
                sb[0] = s;
            }
            int cnt = cntAll[b];
            const unsigned int* seg = p.ebuf + b * BCAP;
            for (int i = t; i < cnt; i += 256)
                atomicAdd(&deg[seg[i] >> 17], 1);
            __syncthreads();
            int v = deg[t];
            scn[t] = v;
            __syncthreads();
            for (int off = 1; off < 256; off <<= 1){
                int xx = (t >= off) ? scn[t - off] : 0;
                __syncthreads();
                scn[t] += xx;
                __syncthreads();
            }
            int excl = scn[t] - v;
            int start = sb[0] + excl;
            int n = b * 256 + t;
            if (n < N_NODES) p.row_ptr[n] = start;
            if (b == NB - 1 && t == 0) p.row_ptr[N_NODES] = sb[0] + cnt;
            deg[t] = start;
            __syncthreads();
            for (int i = t; i < cnt; i += 256){
                unsigned int e = seg[i];
                int pos = atomicAdd(&deg[e >> 17], 1);
                p.esrc[pos] = (int)(e & 0x1FFFFu);
            }
        }
    }
    if (multi) grid.sync();

    // ---------------- P3: layer-1 aggregate ----------------
    if (pm & 8){
        for (int vb = bid; vb < N_NODES / 4; vb += nb){
            int wv = t >> 6, lane = t & 63;
            int n = vb * 4 + wv;
            int g = lane >> 4;
            int l = lane & 15;
            int hd = l >> 2;

            float adh = p.a_d1[(unsigned)(n * 4 + hd)];
            float den = 0.f;
            float acc[8];
            #pragma unroll
            for (int k = 0; k < 8; k++) acc[k] = 0.f;
            const __half* hb = p.h1h + ((unsigned)l << 3);

            if (g == 0){
                float w = __expf(leaky(p.a_s1[(unsigned)(n * 4 + hd)] + adh));
                den = w;
                uint4 r = *(const uint4*)(hb + ((unsigned)n << 7));
                fma8(acc, w, r);
            }
            int start = p.row_ptr[n], end = p.row_ptr[n + 1];
            int len = end - start;
            int chunk = (len + 3) >> 2;
            int i = start + g * chunk;
            int e = i + chunk; if (e > end) e = end;
            for (; i + 3 < e; i += 4){
                int s0 = p.esrc[i], s1 = p.esrc[i + 1], s2 = p.esrc[i + 2], s3 = p.esrc[i + 3];
                float a0 = p.a_s1[(unsigned)(s0 * 4 + hd)];
                float a1 = p.a_s1[(unsigned)(s1 * 4 + hd)];
                float a2 = p.a_s1[(unsigned)(s2 * 4 + hd)];
                float a3 = p.a_s1[(unsigned)(s3 * 4 + hd)];
                uint4 r0 = *(const uint4*)(hb + ((unsigned)s0 << 7));
                uint4 r1 = *(const uint4*)(hb + ((unsigned)s1 << 7));
                uint4 r2 = *(const uint4*)(hb + ((unsigned)s2 << 7));
                uint4 r3 = *(const uint4*)(hb + ((unsigned)s3 << 7));
                float w0 = __expf(leaky(a0 + adh));
                float w1 = __expf(leaky(a1 + adh));
                float w2 = __expf(leaky(a2 + adh));
                float w3 = __expf(leaky(a3 + adh));
                den += (w0 + w1) + (w2 + w3);
                fma8(acc, w0, r0);
                fma8(acc, w1, r1);
                fma8(acc, w2, r2);
                fma8(acc, w3, r3);
            }
            for (; i < e; i++){
                int s0 = p.esrc[i];
                float w0 = __expf(leaky(p.a_s1[(unsigned)(s0 * 4 + hd)] + adh));
                uint4 r0 = *(const uint4*)(hb + ((unsigned)s0 << 7));
                den += w0;
                fma8(acc, w0, r0);
            }
            den += __shfl_xor(den, 16); den += __shfl_xor(den, 32);
            #pragma unroll
            for (int k = 0; k < 8; k++){
                acc[k] += __shfl_xor(acc[k], 16);
                acc[k] += __shfl_xor(acc[k], 32);
            }
            if (g == 0){
                float inv = 1.f / (den + 1e-16f);
                int d0 = l * 8;
                float4 ba = *(const float4*)(p.b1 + d0);
                float4 bb = *(const float4*)(p.b1 + d0 + 4);
                __half2 o[4];
                o[0] = __floats2half2_rn(elu1(acc[0] * inv + ba.x), elu1(acc[1] * inv + ba.y));
                o[1] = __floats2half2_rn(elu1(acc[2] * inv + ba.z), elu1(acc[3] * inv + ba.w));
                o[2] = __floats2half2_rn(elu1(acc[4] * inv + bb.x), elu1(acc[5] * inv + bb.y));
                o[3] = __floats2half2_rn(elu1(acc[6] * inv + bb.z), elu1(acc[7] * inv + bb.w));
                *(uint4*)(p.hL1h + (size_t)n * F1 + d0) = *(uint4*)o;
            }
        }
    }
    if (multi) grid.sync();

    // ---------------- P4: layer-2 dense (fp16 weights in LDS, f32 acc) ----------------
    if (pm & 16){
        for (int vb = bid; vb < N_NODES / 16; vb += nb){
            __syncthreads();
            __half* hs   = (__half*)smem_raw;            // 16 rows x 136 halves (pad kills bank conflicts)
            __half* W2sh = (__half*)(smem_raw + 4352);   // 2048 halves
            {
                int row = t >> 4, q = t & 15;
                ((uint4*)(hs + row * 136))[q] = ((const uint4*)(p.hL1h + (size_t)vb * 2048 + row * 128))[q];
            }
            for (int j = t; j < 2048; j += 256) W2sh[j] = __float2half(p.W2[j]);
            __syncthreads();

            int ln = t >> 4, dim = t & 15;
            int n = vb * 16 + ln;
            float dot = 0.f;
            const __half2* hrow = (const __half2*)(hs + ln * 136);
            #pragma unroll 8
            for (int k2 = 0; k2 < 64; k2++){
                float2 f = __half22float2(hrow[k2]);
                dot += f.x * __half2float(W2sh[(2 * k2) * 16 + dim]);
                dot += f.y * __half2float(W2sh[(2 * k2 + 1) * 16 + dim]);
            }
            float ps = dot * p.as2w[dim];
            float pd = dot * p.ad2w[dim];
            #pragma unroll
            for (int off = 8; off >= 1; off >>= 1){
                ps += __shfl_down(ps, off, 16);
                pd += __shfl_down(pd, off, 16);
            }
            if (dim == 0){ p.a_s2[n] = ps; p.a_d2[n] = pd; }
            p.h2h[(size_t)n * 16 + dim] = __float2half(dot);
        }
    }
    if (multi) grid.sync();

    // ---------------- P5: layer-2 aggregate + classifier ----------------
    if (pm & 32){
        for (int vb = bid; vb < N_NODES / 4; vb += nb){
            int wv = t >> 6, lane = t & 63;
            int n = vb * 4 + wv;
            int g = lane >> 3;
            int l = lane & 7;
            float adn = p.a_d2[n];
            const __half* hb2 = p.h2h + 2 * l;

            float den = 0.f, acc0 = 0.f, acc1 = 0.f;
            if (g == 0){
                float w = __expf(leaky(p.a_s2[n] + adn));
                den = w;
                float2 f = __half22float2(*(const __half2*)(hb2 + ((unsigned)n << 4)));
                acc0 = w * f.x; acc1 = w * f.y;
            }
            int start = p.row_ptr[n], end = p.row_ptr[n + 1];
            int len = end - start;
            int chunk = (len + 7) >> 3;
            int i = start + g * chunk;
            int e = i + chunk; if (e > end) e = end;
            for (; i + 3 < e; i += 4){
                int s0 = p.esrc[i], s1 = p.esrc[i + 1], s2 = p.esrc[i + 2], s3 = p.esrc[i + 3];
                float a0 = p.a_s2[s0], a1 = p.a_s2[s1], a2 = p.a_s2[s2], a3 = p.a_s2[s3];
                __half2 q0 = *(const __half2*)(hb2 + ((unsigned)s0 << 4));
                __half2 q1 = *(const __half2*)(hb2 + ((unsigned)s1 << 4));
                __half2 q2 = *(const __half2*)(hb2 + ((unsigned)s2 << 4));
                __half2 q3 = *(const __half2*)(hb2 + ((unsigned)s3 << 4));
                float w0 = __expf(leaky(a0 + adn));
                float w1 = __expf(leaky(a1 + adn));
                float w2 = __expf(leaky(a2 + adn));
                float w3 = __expf(leaky(a3 + adn));
                den += (w0 + w1) + (w2 + w3);
                float2 f0 = __half22float2(q0), f1 = __half22float2(q1);
                float2 f2 = __half22float2(q2), f3 = __half22float2(q3);
                acc0 += w0 * f0.x + w1 * f1.x + w2 * f2.x + w3 * f3.x;
                acc1 += w0 * f0.y + w1 * f1.y + w2 * f2.y + w3 * f3.y;
            }
            for (; i < e; i++){
                int s0 = p.esrc[i];
                float w0 = __expf(leaky(p.a_s2[s0] + adn));
                float2 f0 = __half22float2(*(const __half2*)(hb2 + ((unsigned)s0 << 4)));
                den += w0;
                acc0 += w0 * f0.x; acc1 += w0 * f0.y;
            }
            #pragma unroll
            for (int off = 8; off <= 32; off <<= 1){
                den  += __shfl_xor(den, off);
                acc0 += __shfl_xor(acc0, off);
                acc1 += __shfl_xor(acc1, off);
            }
            float inv = 1.f / (den + 1e-16f);
            float e0v = elu1(acc0 * inv + p.b2[2 * l]);
            float e1v = elu1(acc1 * inv + p.b2[2 * l + 1]);
            if (g == 0){
                float2 ov; ov.x = e0v; ov.y = e1v;
                *(float2*)(p.out + (size_t)n * 16 + 2 * l) = ov;
            }
            float hid = p.bc1[l];
            #pragma unroll
            for (int j = 0; j < 8; j++){
                float a = __shfl(e0v, j, 8);
                float b = __shfl(e1v, j, 8);
                hid += a * p.Wc1[(2 * j) * 8 + l] + b * p.Wc1[(2 * j + 1) * 8 + l];
            }
            float contrib = fmaxf(hid, 0.f) * p.Wc2[l];
            contrib += __shfl_xor(contrib, 1);
            contrib += __shfl_xor(contrib, 2);
            contrib += __shfl_xor(contrib, 4);
            if (lane == 0) p.out[(size_t)N_NODES * 16 + n] = 1.f / (1.f + __expf(-(contrib + p.bc2[0])));
        }
    }
}

extern "C" void kernel_launch(void* const* d_in, const int* in_sizes, int n_in,
                              void* d_out, int out_size, void* d_ws, size_t ws_size,
                              hipStream_t stream){
    Params p;
    p.x    = (const float*)d_in[0];
    const int* ei = (const int*)d_in[1];
    p.W1   = (const float*)d_in[2];
    p.as1w = (const float*)d_in[3];
    p.ad1w = (const float*)d_in[4];
    p.b1   = (const float*)d_in[5];
    p.W2   = (const float*)d_in[6];
    p.as2w = (const float*)d_in[7];
    p.ad2w = (const float*)d_in[8];
    p.b2   = (const float*)d_in[9];
    p.Wc1  = (const float*)d_in[10];
    p.bc1  = (const float*)d_in[11];
    p.Wc2  = (const float*)d_in[12];
    p.bc2  = (const float*)d_in[13];
    p.out  = (float*)d_out;
    p.src  = ei;
    p.dst  = ei + N_EDGES;

    float* ws = (float*)d_ws;
    p.a_s1 = ws;                                        // N*4
    p.a_d1 = p.a_s1 + (size_t)N_NODES * 4;              // N*4
    p.a_s2 = p.a_d1 + (size_t)N_NODES * 4;              // N
    p.a_d2 = p.a_s2 + N_NODES;                          // N
    p.h1h  = (__half*)(p.a_d2 + N_NODES);               // N*128 f16
    p.hL1h = p.h1h + (size_t)N_NODES * F1;              // N*128 f16
    p.h2h  = p.hL1h + (size_t)N_NODES * F1;             // N*16 f16
    p.bucketCnt = (int*)(p.h2h + (size_t)N_NODES * 16); // NB
    p.row_ptr   = p.bucketCnt + NB;                     // N+1
    p.esrc      = p.row_ptr + N_NODES + 1;              // E
    p.ebuf      = (unsigned int*)(p.esrc + N_EDGES);    // NB*BCAP

    // Cooperative capacity: query, never assume (round-8 lesson).
    int capPerCU = 0;
    hipError_t qerr = hipOccupancyMaxActiveBlocksPerMultiprocessor(
        &capPerCU, (const void*)k_mega, 256, 0);
    int grid = (qerr == hipSuccess) ? capPerCU * 256 : 0;   // 256 CUs on MI355X
    if (grid > NBLK_MAX) grid = NBLK_MAX;

    bool done = false;
    if (grid >= 256){
        int pmAll = 0x3F;
        void* args[] = { &p, &pmAll };
        hipError_t err = hipLaunchCooperativeKernel((const void*)k_mega, dim3(grid), dim3(256),
                                                    args, 0, stream);
        if (err == hipSuccess) done = true;
        else (void)hipGetLastError();   // clear; fall back
    }
    if (!done){
        k_mega<<<391,   256, 0, stream>>>(p, 1);
        k_mega<<<NBLK_BIN + N_NODES / 8, 256, 0, stream>>>(p, 2);
        k_mega<<<NB,    256, 0, stream>>>(p, 4);
        k_mega<<<N_NODES / 4,  256, 0, stream>>>(p, 8);
        k_mega<<<N_NODES / 16, 256, 0, stream>>>(p, 16);
        k_mega<<<N_NODES / 4,  256, 0, stream>>>(p, 32);
    }
}

// Round 10
// 294.158 us; speedup vs baseline: 2.8333x; 2.8333x over previous
//
#include <hip/hip_runtime.h>
#include <hip/hip_fp16.h>
#include <math.h>

#define N_NODES 100000
#define N_EDGES 1600000
#define F_IN 8
#define HID 32
#define HEADS 4
#define F1 128    // HEADS*HID
#define F2 16     // OUT
#define NB 391          // buckets of 256 nodes
#define NBLK_BIN 782    // edge-binning blocks of 2048 edges
#define BCAP 4864       // per-bucket capacity (mean 4092, sd ~64 -> 12 sigma)

__device__ __forceinline__ float leaky(float x){ return x > 0.f ? x : 0.2f * x; }
__device__ __forceinline__ float elu1(float x){ return x > 0.f ? x : __expf(x) - 1.f; }

__device__ __forceinline__ __half2 shfl_xor_h2(__half2 v, int m){
    int iv = *(int*)&v;
    iv = __shfl_xor(iv, m);
    return *(__half2*)&iv;
}

// fp16 packed FMA of one 16B slice (8 halves) into 4 half2 accumulators
__device__ __forceinline__ void pkfma4(__half2* acc, __half2 w2, const uint4& r){
    const __half2* p = (const __half2*)&r;
    #pragma unroll
    for (int k = 0; k < 4; k++) acc[k] = __hfma2(w2, p[k], acc[k]);
}

// ---------------- Fused: edge binning (blocks 0..781) + layer-1 dense (rest) ----------------
__global__ __launch_bounds__(256) void k_build_dense1(
    const int* __restrict__ src, const int* __restrict__ dst,
    int* __restrict__ bucketCnt, unsigned int* __restrict__ ebuf,
    const float* __restrict__ x, const float* __restrict__ W1,
    const float* __restrict__ as1w, const float* __restrict__ ad1w,
    __half* __restrict__ h1h, float* __restrict__ a_s1, float* __restrict__ a_d1){
    __shared__ float smem[1344];
    int t = threadIdx.x;
    if (blockIdx.x < NBLK_BIN){
        // ---- edge binning: 2048 edges -> 391 coarse buckets, line-local writes ----
        int* hist    = (int*)smem;
        int* basePos = hist + NB;
        int* cur     = basePos + NB;
        for (int j = t; j < NB; j += 256) hist[j] = 0;
        __syncthreads();
        int base = blockIdx.x * 2048;
        #pragma unroll
        for (int j = 0; j < 8; j++){
            int e = base + j * 256 + t;
            if (e < N_EDGES) atomicAdd(&hist[dst[e] >> 8], 1);
        }
        __syncthreads();
        for (int j = t; j < NB; j += 256){
            int h = hist[j];
            if (h) basePos[j] = atomicAdd(&bucketCnt[j], h);
            cur[j] = 0;
        }
        __syncthreads();
        #pragma unroll
        for (int j = 0; j < 8; j++){
            int e = base + j * 256 + t;
            if (e < N_EDGES){
                int d = dst[e];
                int b = d >> 8;
                int off = atomicAdd(&cur[b], 1);
                ebuf[b * BCAP + basePos[b] + off] = ((unsigned)(d & 255) << 17) | (unsigned)src[e];
            }
        }
    } else {
        // ---- layer-1 dense: h1 = x@W1 (fp16 out); per-head attention dots ----
        float* W1s  = smem;          // 1024
        float* atts = smem + 1024;   // 128
        float* attd = smem + 1152;   // 128
        float* xs   = smem + 1280;   // 64
        int bid = blockIdx.x - NBLK_BIN;
        ((float4*)W1s)[t] = ((const float4*)W1)[t];
        if (t < 128){ atts[t] = as1w[t]; attd[t] = ad1w[t]; }
        if (t < 64) xs[t] = x[bid * 64 + t];
        __syncthreads();

        int ln = t >> 5, l32 = t & 31;
        int n = bid * 8 + ln;               // N divisible by 8
        float xr[8];
        #pragma unroll
        for (int k = 0; k < 8; k++) xr[k] = xs[ln * 8 + k];
        int j0 = l32 * 4;
        float o0 = 0, o1 = 0, o2 = 0, o3 = 0;
        #pragma unroll
        for (int k = 0; k < 8; k++){
            float4 w4 = ((const float4*)(W1s + k * F1))[l32];
            o0 += xr[k] * w4.x; o1 += xr[k] * w4.y; o2 += xr[k] * w4.z; o3 += xr[k] * w4.w;
        }
        int hd = l32 >> 3;
        int dl = j0 & 31;
        float ps = o0 * atts[hd * 32 + dl] + o1 * atts[hd * 32 + dl + 1]
                 + o2 * atts[hd * 32 + dl + 2] + o3 * atts[hd * 32 + dl + 3];
        float pd = o0 * attd[hd * 32 + dl] + o1 * attd[hd * 32 + dl + 1]
                 + o2 * attd[hd * 32 + dl + 2] + o3 * attd[hd * 32 + dl + 3];
        ps += __shfl_down(ps, 4, 8); ps += __shfl_down(ps, 2, 8); ps += __shfl_down(ps, 1, 8);
        pd += __shfl_down(pd, 4, 8); pd += __shfl_down(pd, 2, 8); pd += __shfl_down(pd, 1, 8);
        if ((l32 & 7) == 0){ a_s1[n * 4 + hd] = ps; a_d1[n * 4 + hd] = pd; }
        __half2* hp = (__half2*)(h1h + (size_t)n * F1 + j0);
        hp[0] = __floats2half2_rn(o0, o1);
        hp[1] = __floats2half2_rn(o2, o3);
    }
}

// ---------------- CSR pass 2: one 256-thread block per bucket ----------------
__global__ __launch_bounds__(256) void k_local_csr(
    const int* __restrict__ bucketCnt, const unsigned int* __restrict__ ebuf,
    int* __restrict__ row_ptr, int* __restrict__ esrc){
    __shared__ int deg[256];
    __shared__ int scn[256];
    __shared__ int cntAll[NB];
    int b = blockIdx.x, t = threadIdx.x;
    deg[t] = 0;
    for (int j = t; j < NB; j += 256) cntAll[j] = bucketCnt[j];
    __syncthreads();
    // parallel bucket-prefix: sum cntAll[0..b) across all 256 threads
    int partial = 0;
    for (int j = t; j < b; j += 256) partial += cntAll[j];
    scn[t] = partial;
    __syncthreads();
    for (int off = 128; off > 0; off >>= 1){
        if (t < off) scn[t] += scn[t + off];
        __syncthreads();
    }
    int sbase = scn[0];
    int cnt = cntAll[b];
    __syncthreads();
    const unsigned int* seg = ebuf + b * BCAP;
    for (int i = t; i < cnt; i += 256)
        atomicAdd(&deg[seg[i] >> 17], 1);
    __syncthreads();
    int v = deg[t];
    scn[t] = v;
    __syncthreads();
    for (int off = 1; off < 256; off <<= 1){
        int xx = (t >= off) ? scn[t - off] : 0;
        __syncthreads();
        scn[t] += xx;
        __syncthreads();
    }
    int excl = scn[t] - v;
    int start = sbase + excl;
    int n = b * 256 + t;
    if (n < N_NODES) row_ptr[n] = start;
    if (b == NB - 1 && t == 0) row_ptr[N_NODES] = sbase + cnt;
    deg[t] = start;            // reuse as global cursor
    __syncthreads();
    for (int i = t; i < cnt; i += 256){
        unsigned int e = seg[i];
        int pos = atomicAdd(&deg[e >> 17], 1);
        esrc[pos] = (int)(e & 0x1FFFFu);
    }
}

// ---------------- Layer 1 aggregate: 4 edge-groups x 16 lanes x 8 dims, fp16 pk-acc, unroll 4 ----------------
__global__ __launch_bounds__(256) void k_agg1(
    const __half* __restrict__ h1h, const float* __restrict__ a_s1, const float* __restrict__ a_d1,
    const int* __restrict__ row_ptr, const int* __restrict__ esrc,
    const float* __restrict__ b1, __half* __restrict__ hL1h){
    int t = threadIdx.x;
    int wv = t >> 6, lane = t & 63;
    int n = blockIdx.x * 4 + wv;               // N divisible by 4
    int g = lane >> 4;                          // edge subgroup (0..3)
    int l = lane & 15;                          // owns dims 8l..8l+7
    int hd = l >> 2;                            // head for these dims

    float adh = a_d1[(unsigned)(n * 4 + hd)];
    float den = 0.f;
    __half2 zero2 = __float2half2_rn(0.f);
    __half2 acc[4] = {zero2, zero2, zero2, zero2};
    const __half* hb = h1h + ((unsigned)l << 3);   // lane's slice base

    if (g == 0){
        // self-loop (softmax shift m=0: logits are O(1); acc scaled by 1/16 for fp16 range)
        float w = __expf(leaky(a_s1[(unsigned)(n * 4 + hd)] + adh));
        den = w;
        uint4 r = *(const uint4*)(hb + ((unsigned)n << 7));
        pkfma4(acc, __float2half2_rn(w * 0.0625f), r);
    }
    int start = row_ptr[n], end = row_ptr[n + 1];
    int len = end - start;
    int chunk = (len + 3) >> 2;
    int i = start + g * chunk;
    int e = i + chunk; if (e > end) e = end;
    for (; i + 3 < e; i += 4){
        int s0 = esrc[i], s1 = esrc[i + 1], s2 = esrc[i + 2], s3 = esrc[i + 3];
        float a0 = a_s1[(unsigned)(s0 * 4 + hd)];
        float a1 = a_s1[(unsigned)(s1 * 4 + hd)];
        float a2 = a_s1[(unsigned)(s2 * 4 + hd)];
        float a3 = a_s1[(unsigned)(s3 * 4 + hd)];
        uint4 r0 = *(const uint4*)(hb + ((unsigned)s0 << 7));
        uint4 r1 = *(const uint4*)(hb + ((unsigned)s1 << 7));
        uint4 r2 = *(const uint4*)(hb + ((unsigned)s2 << 7));
        uint4 r3 = *(const uint4*)(hb + ((unsigned)s3 << 7));
        float w0 = __expf(leaky(a0 + adh));
        float w1 = __expf(leaky(a1 + adh));
        float w2 = __expf(leaky(a2 + adh));
        float w3 = __expf(leaky(a3 + adh));
        den += (w0 + w1) + (w2 + w3);
        pkfma4(acc, __float2half2_rn(w0 * 0.0625f), r0);
        pkfma4(acc, __float2half2_rn(w1 * 0.0625f), r1);
        pkfma4(acc, __float2half2_rn(w2 * 0.0625f), r2);
        pkfma4(acc, __float2half2_rn(w3 * 0.0625f), r3);
    }
    for (; i < e; i++){
        int s0 = esrc[i];
        float w0 = __expf(leaky(a_s1[(unsigned)(s0 * 4 + hd)] + adh));
        uint4 r0 = *(const uint4*)(hb + ((unsigned)s0 << 7));
        den += w0;
        pkfma4(acc, __float2half2_rn(w0 * 0.0625f), r0);
    }
    // combine the four edge-groups (lanes xor16/xor32 share l, hd)
    den += __shfl_xor(den, 16); den += __shfl_xor(den, 32);
    #pragma unroll
    for (int k = 0; k < 4; k++){
        acc[k] = __hadd2(acc[k], shfl_xor_h2(acc[k], 16));
        acc[k] = __hadd2(acc[k], shfl_xor_h2(acc[k], 32));
    }
    if (g == 0){
        float inv = 16.f / (den + 1e-16f);      // x16 undoes the 1/16 acc scaling
        int d0 = l * 8;
        float4 ba = *(const float4*)(b1 + d0);
        float4 bb = *(const float4*)(b1 + d0 + 4);
        float2 f0 = __half22float2(acc[0]);
        float2 f1 = __half22float2(acc[1]);
        float2 f2 = __half22float2(acc[2]);
        float2 f3 = __half22float2(acc[3]);
        __half2 o[4];
        o[0] = __floats2half2_rn(elu1(f0.x * inv + ba.x), elu1(f0.y * inv + ba.y));
        o[1] = __floats2half2_rn(elu1(f1.x * inv + ba.z), elu1(f1.y * inv + ba.w));
        o[2] = __floats2half2_rn(elu1(f2.x * inv + bb.x), elu1(f2.y * inv + bb.y));
        o[3] = __floats2half2_rn(elu1(f3.x * inv + bb.z), elu1(f3.y * inv + bb.w));
        *(uint4*)(hL1h + (size_t)n * F1 + d0) = *(uint4*)o;
    }
}

// ---------------- Layer 2 dense: h2 = hL1@W2 (fp16 in/out) ; a_s2/a_d2 ----------------
__global__ __launch_bounds__(256) void k_dense2(
    const __half* __restrict__ hL1h, const float* __restrict__ W2,
    const float* __restrict__ as2w, const float* __restrict__ ad2w,
    __half* __restrict__ h2h, float* __restrict__ a_s2, float* __restrict__ a_d2){
    __shared__ float W2s[F1 * F2];     // 8 KB
    __shared__ __half hs[16 * F1];     // 4 KB
    int t = threadIdx.x;
    ((float4*)W2s)[t]       = ((const float4*)W2)[t];
    ((float4*)W2s)[t + 256] = ((const float4*)W2)[t + 256];
    ((uint4*)hs)[t] = ((const uint4*)(hL1h + (size_t)blockIdx.x * 16 * F1))[t];
    __syncthreads();

    int ln = t >> 4, dim = t & 15;
    int n = blockIdx.x * 16 + ln;      // N divisible by 16
    float dot = 0.f;
    const __half2* hrow = (const __half2*)(hs + ln * F1);
    #pragma unroll 8
    for (int k2 = 0; k2 < 64; k2++){
        float2 f = __half22float2(hrow[k2]);
        dot += f.x * W2s[(2 * k2) * 16 + dim];
        dot += f.y * W2s[(2 * k2 + 1) * 16 + dim];
    }
    float ps = dot * as2w[dim];
    float pd = dot * ad2w[dim];
    #pragma unroll
    for (int off = 8; off >= 1; off >>= 1){
        ps += __shfl_down(ps, off, 16);
        pd += __shfl_down(pd, off, 16);
    }
    if (dim == 0){ a_s2[n] = ps; a_d2[n] = pd; }
    h2h[(size_t)n * 16 + dim] = __float2half(dot);
}

// ---------------- Layer 2 aggregate + classifier: 16 edge-groups x 4 lanes x 4 dims ----------------
__global__ __launch_bounds__(256) void k_agg2(
    const __half* __restrict__ h2h, const float* __restrict__ a_s2, const float* __restrict__ a_d2,
    const int* __restrict__ row_ptr, const int* __restrict__ esrc,
    const float* __restrict__ b2, const float* __restrict__ Wc1, const float* __restrict__ bc1,
    const float* __restrict__ Wc2, const float* __restrict__ bc2, float* __restrict__ out){
    int t = threadIdx.x;
    int wv = t >> 6, lane = t & 63;
    int n = blockIdx.x * 4 + wv;       // N divisible by 4
    int g = lane >> 2;                 // edge subgroup (0..15)
    int l = lane & 3;                  // owns dims 4l..4l+3
    float adn = a_d2[n];
    const __half* hb2 = h2h + 4 * l;

    float den = 0.f, acc0 = 0.f, acc1 = 0.f, acc2 = 0.f, acc3 = 0.f;
    if (g == 0){
        float w = __expf(leaky(a_s2[n] + adn));
        den = w;
        uint2 q = *(const uint2*)(hb2 + ((unsigned)n << 4));
        float2 fa = __half22float2(*(__half2*)&q.x);
        float2 fb = __half22float2(*(__half2*)&q.y);
        acc0 = w * fa.x; acc1 = w * fa.y; acc2 = w * fb.x; acc3 = w * fb.y;
    }
    int start = row_ptr[n], end = row_ptr[n + 1];
    int len = end - start;
    int chunk = (len + 15) >> 4;
    int i = start + g * chunk;
    int e = i + chunk; if (e > end) e = end;
    for (; i + 1 < e; i += 2){
        int s0 = esrc[i], s1 = esrc[i + 1];
        float a0 = a_s2[s0], a1 = a_s2[s1];
        uint2 q0 = *(const uint2*)(hb2 + ((unsigned)s0 << 4));
        uint2 q1 = *(const uint2*)(hb2 + ((unsigned)s1 << 4));
        float w0 = __expf(leaky(a0 + adn));
        float w1 = __expf(leaky(a1 + adn));
        den += w0 + w1;
        float2 f0a = __half22float2(*(__half2*)&q0.x);
        float2 f0b = __half22float2(*(__half2*)&q0.y);
        float2 f1a = __half22float2(*(__half2*)&q1.x);
        float2 f1b = __half22float2(*(__half2*)&q1.y);
        acc0 += w0 * f0a.x + w1 * f1a.x;
        acc1 += w0 * f0a.y + w1 * f1a.y;
        acc2 += w0 * f0b.x + w1 * f1b.x;
        acc3 += w0 * f0b.y + w1 * f1b.y;
    }
    if (i < e){
        int s0 = esrc[i];
        float w0 = __expf(leaky(a_s2[s0] + adn));
        uint2 q0 = *(const uint2*)(hb2 + ((unsigned)s0 << 4));
        float2 f0a = __half22float2(*(__half2*)&q0.x);
        float2 f0b = __half22float2(*(__half2*)&q0.y);
        den += w0;
        acc0 += w0 * f0a.x; acc1 += w0 * f0a.y;
        acc2 += w0 * f0b.x; acc3 += w0 * f0b.y;
    }
    // combine the 16 edge-groups (butterfly over lane bits 2..5); all lanes end with sums
    #pragma unroll
    for (int off = 4; off <= 32; off <<= 1){
        den  += __shfl_xor(den, off);
        acc0 += __shfl_xor(acc0, off);
        acc1 += __shfl_xor(acc1, off);
        acc2 += __shfl_xor(acc2, off);
        acc3 += __shfl_xor(acc3, off);
    }
    float inv = 1.f / (den + 1e-16f);
    int d0 = 4 * l;
    float4 bv = *(const float4*)(b2 + d0);
    float e0 = elu1(acc0 * inv + bv.x);
    float e1 = elu1(acc1 * inv + bv.y);
    float e2 = elu1(acc2 * inv + bv.z);
    float e3 = elu1(acc3 * inv + bv.w);
    if (g == 0){
        float4 ov; ov.x = e0; ov.y = e1; ov.z = e2; ov.w = e3;
        *(float4*)(out + (size_t)n * 16 + d0) = ov;
    }
    // classifier: every 4-lane cluster holds the full 16-dim emb; u = lane&7 hidden unit
    int u = lane & 7;
    int base = lane & ~3;
    float hid = bc1[u];
    #pragma unroll
    for (int d = 0; d < 16; d++){
        float ev = d % 4 == 0 ? e0 : d % 4 == 1 ? e1 : d % 4 == 2 ? e2 : e3;
        float v = __shfl(ev, base + (d >> 2), 64);
        hid += v * Wc1[d * 8 + u];
    }
    float contrib = fmaxf(hid, 0.f) * Wc2[u];
    contrib += __shfl_xor(contrib, 1);
    contrib += __shfl_xor(contrib, 2);
    contrib += __shfl_xor(contrib, 4);
    if (lane == 0) out[(size_t)N_NODES * 16 + n] = 1.f / (1.f + __expf(-(contrib + bc2[0])));
}

extern "C" void kernel_launch(void* const* d_in, const int* in_sizes, int n_in,
                              void* d_out, int out_size, void* d_ws, size_t ws_size,
                              hipStream_t stream){
    const float* x    = (const float*)d_in[0];
    const int*   ei   = (const int*)d_in[1];
    const float* W1   = (const float*)d_in[2];
    const float* as1w = (const float*)d_in[3];
    const float* ad1w = (const float*)d_in[4];
    const float* b1   = (const float*)d_in[5];
    const float* W2   = (const float*)d_in[6];
    const float* as2w = (const float*)d_in[7];
    const float* ad2w = (const float*)d_in[8];
    const float* b2   = (const float*)d_in[9];
    const float* Wc1  = (const float*)d_in[10];
    const float* bc1  = (const float*)d_in[11];
    const float* Wc2  = (const float*)d_in[12];
    const float* bc2  = (const float*)d_in[13];
    float* out = (float*)d_out;
    const int* src = ei;
    const int* dst = ei + N_EDGES;

    float* ws   = (float*)d_ws;
    float* a_s1 = ws;                                   // N*4
    float* a_d1 = a_s1 + (size_t)N_NODES * 4;           // N*4
    float* a_s2 = a_d1 + (size_t)N_NODES * 4;           // N
    float* a_d2 = a_s2 + N_NODES;                       // N
    __half* h1h  = (__half*)(a_d2 + N_NODES);           // N*128 f16
    __half* hL1h = h1h + (size_t)N_NODES * F1;          // N*128 f16
    __half* h2h  = hL1h + (size_t)N_NODES * F1;         // N*16 f16
    int* bucketCnt = (int*)(h2h + (size_t)N_NODES * 16);// NB
    int* row_ptr  = bucketCnt + NB;                     // N+1
    int* esrc     = row_ptr + N_NODES + 1;              // E
    unsigned int* ebuf = (unsigned int*)(esrc + N_EDGES); // NB*BCAP

    hipMemsetAsync(bucketCnt, 0, NB * sizeof(int), stream);
    k_build_dense1<<<NBLK_BIN + N_NODES / 8, 256, 0, stream>>>(
        src, dst, bucketCnt, ebuf, x, W1, as1w, ad1w, h1h, a_s1, a_d1);
    k_local_csr<<<NB, 256, 0, stream>>>(bucketCnt, ebuf, row_ptr, esrc);
    k_agg1<<<N_NODES / 4, 256, 0, stream>>>(h1h, a_s1, a_d1, row_ptr, esrc, b1, hL1h);
    k_dense2<<<N_NODES / 16, 256, 0, stream>>>(hL1h, W2, as2w, ad2w, h2h, a_s2, a_d2);
    k_agg2<<<N_NODES / 4, 256, 0, stream>>>(h2h, a_s2, a_d2, row_ptr, esrc, b2, Wc1, bc1, Wc2, bc2, out);
}

// Round 11
// 279.318 us; speedup vs baseline: 2.9838x; 1.0531x over previous
//
#include <hip/hip_runtime.h>
#include <hip/hip_fp16.h>
#include <math.h>

#define N_NODES 100000
#define N_EDGES 1600000
#define F_IN 8
#define HID 32
#define HEADS 4
#define F1 128    // HEADS*HID
#define F2 16     // OUT
#define NB 391          // buckets of 256 nodes
#define NBLK_BIN 391    // edge-binning blocks of 4096 edges
#define BCAP 4864       // per-bucket capacity (mean 4092, sd ~64 -> 12 sigma)

__device__ __forceinline__ float leaky(float x){ return x > 0.f ? x : 0.2f * x; }
__device__ __forceinline__ float elu1(float x){ return x > 0.f ? x : __expf(x) - 1.f; }

__device__ __forceinline__ __half2 shfl_xor_h2(__half2 v, int m){
    int iv = *(int*)&v;
    iv = __shfl_xor(iv, m);
    return *(__half2*)&iv;
}

// fp16 packed FMA of one 16B slice (8 halves) into 4 half2 accumulators
__device__ __forceinline__ void pkfma4(__half2* acc, __half2 w2, const uint4& r){
    const __half2* p = (const __half2*)&r;
    #pragma unroll
    for (int k = 0; k < 4; k++) acc[k] = __hfma2(w2, p[k], acc[k]);
}

// ---------------- Fused: edge binning (blocks 0..390) + layer-1 dense (rest) ----------------
__global__ __launch_bounds__(256) void k_build_dense1(
    const int* __restrict__ src, const int* __restrict__ dst,
    int* __restrict__ bucketCnt, unsigned int* __restrict__ ebuf,
    const float* __restrict__ x, const float* __restrict__ W1,
    const float* __restrict__ as1w, const float* __restrict__ ad1w,
    __half* __restrict__ h1h, float* __restrict__ a_s1, float* __restrict__ a_d1){
    __shared__ float smem[1344];
    int t = threadIdx.x;
    if (blockIdx.x < NBLK_BIN){
        // ---- edge binning: 4096 edges -> 391 coarse buckets, line-local writes ----
        int* hist    = (int*)smem;
        int* basePos = hist + NB;
        int* cur     = basePos + NB;
        for (int j = t; j < NB; j += 256) hist[j] = 0;
        __syncthreads();
        int base = blockIdx.x * 4096;
        int dv[16];                        // register-cache dst (skip re-read in scatter pass)
        #pragma unroll
        for (int j = 0; j < 16; j++){
            int e = base + j * 256 + t;
            dv[j] = (e < N_EDGES) ? dst[e] : -1;
            if (dv[j] >= 0) atomicAdd(&hist[dv[j] >> 8], 1);
        }
        __syncthreads();
        for (int j = t; j < NB; j += 256){
            int h = hist[j];
            if (h) basePos[j] = atomicAdd(&bucketCnt[j], h);
            cur[j] = 0;
        }
        __syncthreads();
        #pragma unroll
        for (int j = 0; j < 16; j++){
            if (dv[j] >= 0){
                int e = base + j * 256 + t;
                int d = dv[j];
                int b = d >> 8;
                int off = atomicAdd(&cur[b], 1);
                ebuf[b * BCAP + basePos[b] + off] = ((unsigned)(d & 255) << 17) | (unsigned)src[e];
            }
        }
    } else {
        // ---- layer-1 dense: h1 = x@W1 (fp16 out); per-head attention dots ----
        float* W1s  = smem;          // 1024
        float* atts = smem + 1024;   // 128
        float* attd = smem + 1152;   // 128
        float* xs   = smem + 1280;   // 64
        int bid = blockIdx.x - NBLK_BIN;
        ((float4*)W1s)[t] = ((const float4*)W1)[t];
        if (t < 128){ atts[t] = as1w[t]; attd[t] = ad1w[t]; }
        if (t < 64) xs[t] = x[bid * 64 + t];
        __syncthreads();

        int ln = t >> 5, l32 = t & 31;
        int n = bid * 8 + ln;               // N divisible by 8
        float xr[8];
        #pragma unroll
        for (int k = 0; k < 8; k++) xr[k] = xs[ln * 8 + k];
        int j0 = l32 * 4;
        float o0 = 0, o1 = 0, o2 = 0, o3 = 0;
        #pragma unroll
        for (int k = 0; k < 8; k++){
            float4 w4 = ((const float4*)(W1s + k * F1))[l32];
            o0 += xr[k] * w4.x; o1 += xr[k] * w4.y; o2 += xr[k] * w4.z; o3 += xr[k] * w4.w;
        }
        int hd = l32 >> 3;
        int dl = j0 & 31;
        float ps = o0 * atts[hd * 32 + dl] + o1 * atts[hd * 32 + dl + 1]
                 + o2 * atts[hd * 32 + dl + 2] + o3 * atts[hd * 32 + dl + 3];
        float pd = o0 * attd[hd * 32 + dl] + o1 * attd[hd * 32 + dl + 1]
                 + o2 * attd[hd * 32 + dl + 2] + o3 * attd[hd * 32 + dl + 3];
        ps += __shfl_down(ps, 4, 8); ps += __shfl_down(ps, 2, 8); ps += __shfl_down(ps, 1, 8);
        pd += __shfl_down(pd, 4, 8); pd += __shfl_down(pd, 2, 8); pd += __shfl_down(pd, 1, 8);
        if ((l32 & 7) == 0){ a_s1[n * 4 + hd] = ps; a_d1[n * 4 + hd] = pd; }
        __half2* hp = (__half2*)(h1h + (size_t)n * F1 + j0);
        hp[0] = __floats2half2_rn(o0, o1);
        hp[1] = __floats2half2_rn(o2, o3);
    }
}

// ---------------- CSR pass 2: one 256-thread block per bucket ----------------
__global__ __launch_bounds__(256) void k_local_csr(
    const int* __restrict__ bucketCnt, const unsigned int* __restrict__ ebuf,
    int* __restrict__ row_ptr, int* __restrict__ esrc){
    __shared__ int deg[256];
    __shared__ int scn[256];
    __shared__ int cntAll[NB];
    int b = blockIdx.x, t = threadIdx.x;
    deg[t] = 0;
    for (int j = t; j < NB; j += 256) cntAll[j] = bucketCnt[j];
    __syncthreads();
    // parallel bucket-prefix: sum cntAll[0..b) across all 256 threads
    int partial = 0;
    for (int j = t; j < b; j += 256) partial += cntAll[j];
    scn[t] = partial;
    __syncthreads();
    for (int off = 128; off > 0; off >>= 1){
        if (t < off) scn[t] += scn[t + off];
        __syncthreads();
    }
    int sbase = scn[0];
    int cnt = cntAll[b];
    __syncthreads();
    const unsigned int* seg = ebuf + b * BCAP;
    for (int i = t; i < cnt; i += 256)
        atomicAdd(&deg[seg[i] >> 17], 1);
    __syncthreads();
    int v = deg[t];
    scn[t] = v;
    __syncthreads();
    for (int off = 1; off < 256; off <<= 1){
        int xx = (t >= off) ? scn[t - off] : 0;
        __syncthreads();
        scn[t] += xx;
        __syncthreads();
    }
    int excl = scn[t] - v;
    int start = sbase + excl;
    int n = b * 256 + t;
    if (n < N_NODES) row_ptr[n] = start;
    if (b == NB - 1 && t == 0) row_ptr[N_NODES] = sbase + cnt;
    deg[t] = start;            // reuse as global cursor
    __syncthreads();
    for (int i = t; i < cnt; i += 256){
        unsigned int e = seg[i];
        int pos = atomicAdd(&deg[e >> 17], 1);
        esrc[pos] = (int)(e & 0x1FFFFu);
    }
}

// ---------------- Layer 1 aggregate: 4 edge-groups x 16 lanes x 8 dims, fp16 pk-acc, unroll 4 ----------------
__global__ __launch_bounds__(256) void k_agg1(
    const __half* __restrict__ h1h, const float* __restrict__ a_s1, const float* __restrict__ a_d1,
    const int* __restrict__ row_ptr, const int* __restrict__ esrc,
    const float* __restrict__ b1, __half* __restrict__ hL1h){
    int t = threadIdx.x;
    int wv = t >> 6, lane = t & 63;
    int n = blockIdx.x * 4 + wv;               // N divisible by 4
    int g = lane >> 4;                          // edge subgroup (0..3)
    int l = lane & 15;                          // owns dims 8l..8l+7
    int hd = l >> 2;                            // head for these dims

    float adh = a_d1[(unsigned)(n * 4 + hd)];
    float den = 0.f;
    __half2 zero2 = __float2half2_rn(0.f);
    __half2 acc[4] = {zero2, zero2, zero2, zero2};
    const __half* hb = h1h + ((unsigned)l << 3);   // lane's slice base

    if (g == 0){
        // self-loop (softmax shift m=0: logits are O(1); acc scaled by 1/16 for fp16 range)
        float w = __expf(leaky(a_s1[(unsigned)(n * 4 + hd)] + adh));
        den = w;
        uint4 r = *(const uint4*)(hb + ((unsigned)n << 7));
        pkfma4(acc, __float2half2_rn(w * 0.0625f), r);
    }
    int start = row_ptr[n], end = row_ptr[n + 1];
    int len = end - start;
    int chunk = (len + 3) >> 2;
    int i = start + g * chunk;
    int e = i + chunk; if (e > end) e = end;
    for (; i + 3 < e; i += 4){
        int s0 = esrc[i], s1 = esrc[i + 1], s2 = esrc[i + 2], s3 = esrc[i + 3];
        float a0 = a_s1[(unsigned)(s0 * 4 + hd)];
        float a1 = a_s1[(unsigned)(s1 * 4 + hd)];
        float a2 = a_s1[(unsigned)(s2 * 4 + hd)];
        float a3 = a_s1[(unsigned)(s3 * 4 + hd)];
        uint4 r0 = *(const uint4*)(hb + ((unsigned)s0 << 7));
        uint4 r1 = *(const uint4*)(hb + ((unsigned)s1 << 7));
        uint4 r2 = *(const uint4*)(hb + ((unsigned)s2 << 7));
        uint4 r3 = *(const uint4*)(hb + ((unsigned)s3 << 7));
        float w0 = __expf(leaky(a0 + adh));
        float w1 = __expf(leaky(a1 + adh));
        float w2 = __expf(leaky(a2 + adh));
        float w3 = __expf(leaky(a3 + adh));
        den += (w0 + w1) + (w2 + w3);
        pkfma4(acc, __float2half2_rn(w0 * 0.0625f), r0);
        pkfma4(acc, __float2half2_rn(w1 * 0.0625f), r1);
        pkfma4(acc, __float2half2_rn(w2 * 0.0625f), r2);
        pkfma4(acc, __float2half2_rn(w3 * 0.0625f), r3);
    }
    for (; i < e; i++){
        int s0 = esrc[i];
        float w0 = __expf(leaky(a_s1[(unsigned)(s0 * 4 + hd)] + adh));
        uint4 r0 = *(const uint4*)(hb + ((unsigned)s0 << 7));
        den += w0;
        pkfma4(acc, __float2half2_rn(w0 * 0.0625f), r0);
    }
    // combine the four edge-groups (lanes xor16/xor32 share l, hd)
    den += __shfl_xor(den, 16); den += __shfl_xor(den, 32);
    #pragma unroll
    for (int k = 0; k < 4; k++){
        acc[k] = __hadd2(acc[k], shfl_xor_h2(acc[k], 16));
        acc[k] = __hadd2(acc[k], shfl_xor_h2(acc[k], 32));
    }
    if (g == 0){
        float inv = 16.f / (den + 1e-16f);      // x16 undoes the 1/16 acc scaling
        int d0 = l * 8;
        float4 ba = *(const float4*)(b1 + d0);
        float4 bb = *(const float4*)(b1 + d0 + 4);
        float2 f0 = __half22float2(acc[0]);
        float2 f1 = __half22float2(acc[1]);
        float2 f2 = __half22float2(acc[2]);
        float2 f3 = __half22float2(acc[3]);
        __half2 o[4];
        o[0] = __floats2half2_rn(elu1(f0.x * inv + ba.x), elu1(f0.y * inv + ba.y));
        o[1] = __floats2half2_rn(elu1(f1.x * inv + ba.z), elu1(f1.y * inv + ba.w));
        o[2] = __floats2half2_rn(elu1(f2.x * inv + bb.x), elu1(f2.y * inv + bb.y));
        o[3] = __floats2half2_rn(elu1(f3.x * inv + bb.z), elu1(f3.y * inv + bb.w));
        *(uint4*)(hL1h + (size_t)n * F1 + d0) = *(uint4*)o;
    }
}

// ---------------- Layer 2 dense: h2 = hL1@W2 (fp16 in/out) ; a_s2/a_d2 ----------------
__global__ __launch_bounds__(256) void k_dense2(
    const __half* __restrict__ hL1h, const float* __restrict__ W2,
    const float* __restrict__ as2w, const float* __restrict__ ad2w,
    __half* __restrict__ h2h, float* __restrict__ a_s2, float* __restrict__ a_d2){
    __shared__ float W2s[F1 * F2];     // 8 KB
    __shared__ __half hs[16 * F1];     // 4 KB
    int t = threadIdx.x;
    ((float4*)W2s)[t]       = ((const float4*)W2)[t];
    ((float4*)W2s)[t + 256] = ((const float4*)W2)[t + 256];
    ((uint4*)hs)[t] = ((const uint4*)(hL1h + (size_t)blockIdx.x * 16 * F1))[t];
    __syncthreads();

    int ln = t >> 4, dim = t & 15;
    int n = blockIdx.x * 16 + ln;      // N divisible by 16
    float dot = 0.f;
    const __half2* hrow = (const __half2*)(hs + ln * F1);
    #pragma unroll 8
    for (int k2 = 0; k2 < 64; k2++){
        float2 f = __half22float2(hrow[k2]);
        dot += f.x * W2s[(2 * k2) * 16 + dim];
        dot += f.y * W2s[(2 * k2 + 1) * 16 + dim];
    }
    float ps = dot * as2w[dim];
    float pd = dot * ad2w[dim];
    #pragma unroll
    for (int off = 8; off >= 1; off >>= 1){
        ps += __shfl_down(ps, off, 16);
        pd += __shfl_down(pd, off, 16);
    }
    if (dim == 0){ a_s2[n] = ps; a_d2[n] = pd; }
    h2h[(size_t)n * 16 + dim] = __float2half(dot);
}

// ---------------- Layer 2 aggregate + classifier: 8 edge-groups x 8 lanes x 2 dims, unroll 4 ----------------
__global__ __launch_bounds__(256) void k_agg2(
    const __half* __restrict__ h2h, const float* __restrict__ a_s2, const float* __restrict__ a_d2,
    const int* __restrict__ row_ptr, const int* __restrict__ esrc,
    const float* __restrict__ b2, const float* __restrict__ Wc1, const float* __restrict__ bc1,
    const float* __restrict__ Wc2, const float* __restrict__ bc2, float* __restrict__ out){
    int t = threadIdx.x;
    int wv = t >> 6, lane = t & 63;
    int n = blockIdx.x * 4 + wv;       // N divisible by 4
    int g = lane >> 3;                 // edge subgroup (0..7)
    int l = lane & 7;                  // owns dims 2l, 2l+1
    float adn = a_d2[n];
    const __half* hb2 = h2h + 2 * l;

    float den = 0.f, acc0 = 0.f, acc1 = 0.f;
    if (g == 0){
        float w = __expf(leaky(a_s2[n] + adn));
        den = w;
        float2 f = __half22float2(*(const __half2*)(hb2 + ((unsigned)n << 4)));
        acc0 = w * f.x; acc1 = w * f.y;
    }
    int start = row_ptr[n], end = row_ptr[n + 1];
    int len = end - start;
    int chunk = (len + 7) >> 3;
    int i = start + g * chunk;
    int e = i + chunk; if (e > end) e = end;
    for (; i + 3 < e; i += 4){
        int s0 = esrc[i], s1 = esrc[i + 1], s2 = esrc[i + 2], s3 = esrc[i + 3];
        float a0 = a_s2[s0], a1 = a_s2[s1], a2 = a_s2[s2], a3 = a_s2[s3];
        __half2 p0 = *(const __half2*)(hb2 + ((unsigned)s0 << 4));
        __half2 p1 = *(const __half2*)(hb2 + ((unsigned)s1 << 4));
        __half2 p2 = *(const __half2*)(hb2 + ((unsigned)s2 << 4));
        __half2 p3 = *(const __half2*)(hb2 + ((unsigned)s3 << 4));
        float w0 = __expf(leaky(a0 + adn));
        float w1 = __expf(leaky(a1 + adn));
        float w2 = __expf(leaky(a2 + adn));
        float w3 = __expf(leaky(a3 + adn));
        den += (w0 + w1) + (w2 + w3);
        float2 f0 = __half22float2(p0), f1 = __half22float2(p1);
        float2 f2 = __half22float2(p2), f3 = __half22float2(p3);
        acc0 += w0 * f0.x + w1 * f1.x + w2 * f2.x + w3 * f3.x;
        acc1 += w0 * f0.y + w1 * f1.y + w2 * f2.y + w3 * f3.y;
    }
    for (; i < e; i++){
        int s0 = esrc[i];
        float w0 = __expf(leaky(a_s2[s0] + adn));
        float2 f0 = __half22float2(*(const __half2*)(hb2 + ((unsigned)s0 << 4)));
        den += w0;
        acc0 += w0 * f0.x; acc1 += w0 * f0.y;
    }
    #pragma unroll
    for (int off = 8; off <= 32; off <<= 1){
        den  += __shfl_xor(den, off);
        acc0 += __shfl_xor(acc0, off);
        acc1 += __shfl_xor(acc1, off);
    }
    float inv = 1.f / (den + 1e-16f);
    float e0v = elu1(acc0 * inv + b2[2 * l]);
    float e1v = elu1(acc1 * inv + b2[2 * l + 1]);
    if (g == 0){
        float2 ov; ov.x = e0v; ov.y = e1v;
        *(float2*)(out + (size_t)n * 16 + 2 * l) = ov;
    }
    // classifier: each 8-lane cluster computes the full hidden layer redundantly
    float hid = bc1[l];
    #pragma unroll
    for (int j = 0; j < 8; j++){
        float a = __shfl(e0v, j, 8);
        float b = __shfl(e1v, j, 8);
        hid += a * Wc1[(2 * j) * 8 + l] + b * Wc1[(2 * j + 1) * 8 + l];
    }
    float contrib = fmaxf(hid, 0.f) * Wc2[l];
    contrib += __shfl_xor(contrib, 1);
    contrib += __shfl_xor(contrib, 2);
    contrib += __shfl_xor(contrib, 4);
    if (lane == 0) out[(size_t)N_NODES * 16 + n] = 1.f / (1.f + __expf(-(contrib + bc2[0])));
}

extern "C" void kernel_launch(void* const* d_in, const int* in_sizes, int n_in,
                              void* d_out, int out_size, void* d_ws, size_t ws_size,
                              hipStream_t stream){
    const float* x    = (const float*)d_in[0];
    const int*   ei   = (const int*)d_in[1];
    const float* W1   = (const float*)d_in[2];
    const float* as1w = (const float*)d_in[3];
    const float* ad1w = (const float*)d_in[4];
    const float* b1   = (const float*)d_in[5];
    const float* W2   = (const float*)d_in[6];
    const float* as2w = (const float*)d_in[7];
    const float* ad2w = (const float*)d_in[8];
    const float* b2   = (const float*)d_in[9];
    const float* Wc1  = (const float*)d_in[10];
    const float* bc1  = (const float*)d_in[11];
    const float* Wc2  = (const float*)d_in[12];
    const float* bc2  = (const float*)d_in[13];
    float* out = (float*)d_out;
    const int* src = ei;
    const int* dst = ei + N_EDGES;

    float* ws   = (float*)d_ws;
    float* a_s1 = ws;                                   // N*4
    float* a_d1 = a_s1 + (size_t)N_NODES * 4;           // N*4
    float* a_s2 = a_d1 + (size_t)N_NODES * 4;           // N
    float* a_d2 = a_s2 + N_NODES;                       // N
    __half* h1h  = (__half*)(a_d2 + N_NODES);           // N*128 f16
    __half* hL1h = h1h + (size_t)N_NODES * F1;          // N*128 f16
    __half* h2h  = hL1h + (size_t)N_NODES * F1;         // N*16 f16
    int* bucketCnt = (int*)(h2h + (size_t)N_NODES * 16);// NB
    int* row_ptr  = bucketCnt + NB;                     // N+1
    int* esrc     = row_ptr + N_NODES + 1;              // E
    unsigned int* ebuf = (unsigned int*)(esrc + N_EDGES); // NB*BCAP

    hipMemsetAsync(bucketCnt, 0, NB * sizeof(int), stream);
    k_build_dense1<<<NBLK_BIN + N_NODES / 8, 256, 0, stream>>>(
        src, dst, bucketCnt, ebuf, x, W1, as1w, ad1w, h1h, a_s1, a_d1);
    k_local_csr<<<NB, 256, 0, stream>>>(bucketCnt, ebuf, row_ptr, esrc);
    k_agg1<<<N_NODES / 4, 256, 0, stream>>>(h1h, a_s1, a_d1, row_ptr, esrc, b1, hL1h);
    k_dense2<<<N_NODES / 16, 256, 0, stream>>>(hL1h, W2, as2w, ad2w, h2h, a_s2, a_d2);
    k_agg2<<<N_NODES / 4, 256, 0, stream>>>(h2h, a_s2, a_d2, row_ptr, esrc, b2, Wc1, bc1, Wc2, bc2, out);
}